// Round 1
// baseline (121.245 us; speedup 1.0000x reference)
//
#include <hip/hip_runtime.h>
#include <math.h>

#define BB 8
#define NN 4096
#define PP 16
#define HH 128
#define SS 32          // n-slices
#define NS 128         // n per slice = NN/SS
#define HID 128
#define RD 64
#define EPSF 1e-6f

// Partials per (b, slice): S0[p], S1[p][h], S2[p][h], M[p][h]
__global__ __launch_bounds__(256) void k1_partials(
    const float* __restrict__ point,   // [B][N][H]
    const float* __restrict__ assign,  // [B][N][P]
    float* __restrict__ wsS1, float* __restrict__ wsS2,
    float* __restrict__ wsM,  float* __restrict__ wsS0)
{
    __shared__ float lds_a[NS * PP];        // 8 KB, assign slice
    __shared__ float red[3 * PP * HH];      // 24 KB, cross-sub reduction
    const int blk = blockIdx.x;             // b*SS + s
    const int b = blk >> 5;                 // / SS
    const int s = blk & (SS - 1);
    const int n0 = s * NS;
    const int tid = threadIdx.x;
    const int h = tid & (HH - 1);
    const int sub = tid >> 7;               // 0 or 1

    // stage assign slice: NS*PP = 2048 floats, fully coalesced
    const float* aptr = assign + (size_t)b * NN * PP + (size_t)n0 * PP;
    #pragma unroll
    for (int j = 0; j < (NS * PP) / 256; ++j)
        lds_a[tid + 256 * j] = aptr[tid + 256 * j];
    __syncthreads();

    float s1[PP], s2[PP], m[PP];
    #pragma unroll
    for (int p = 0; p < PP; ++p) { s1[p] = 0.f; s2[p] = 0.f; m[p] = -INFINITY; }

    const float* xptr = point + (size_t)b * NN * HH + (size_t)n0 * HH + h;
    for (int nn = sub; nn < NS; nn += 2) {
        float x = xptr[(size_t)nn * HH];
        #pragma unroll
        for (int q = 0; q < 4; ++q) {
            // wave-uniform 16B LDS read -> ds_read_b128 broadcast
            float4 av = *(const float4*)&lds_a[nn * PP + 4 * q];
            float a0 = av.x, a1 = av.y, a2 = av.z, a3 = av.w;
            float t;
            t = a0 * x; s1[4*q+0] += t; s2[4*q+0] = fmaf(t, x, s2[4*q+0]);
            if (a0 > EPSF) m[4*q+0] = fmaxf(m[4*q+0], t);
            t = a1 * x; s1[4*q+1] += t; s2[4*q+1] = fmaf(t, x, s2[4*q+1]);
            if (a1 > EPSF) m[4*q+1] = fmaxf(m[4*q+1], t);
            t = a2 * x; s1[4*q+2] += t; s2[4*q+2] = fmaf(t, x, s2[4*q+2]);
            if (a2 > EPSF) m[4*q+2] = fmaxf(m[4*q+2], t);
            t = a3 * x; s1[4*q+3] += t; s2[4*q+3] = fmaf(t, x, s2[4*q+3]);
            if (a3 > EPSF) m[4*q+3] = fmaxf(m[4*q+3], t);
        }
    }

    // per-p assignment mass over this slice (threads 0..15)
    float s0 = 0.f;
    if (tid < PP) {
        #pragma unroll 8
        for (int nn = 0; nn < NS; ++nn) s0 += lds_a[nn * PP + tid];
    }

    // combine sub=1 into sub=0
    __syncthreads();
    if (sub) {
        #pragma unroll
        for (int p = 0; p < PP; ++p) {
            red[p * HH + h]               = s1[p];
            red[PP * HH + p * HH + h]     = s2[p];
            red[2 * PP * HH + p * HH + h] = m[p];
        }
    }
    __syncthreads();
    if (!sub) {
        size_t base = (size_t)blk * PP * HH + h;
        #pragma unroll
        for (int p = 0; p < PP; ++p) {
            float r1 = s1[p] + red[p * HH + h];
            float r2 = s2[p] + red[PP * HH + p * HH + h];
            float rm = fmaxf(m[p], red[2 * PP * HH + p * HH + h]);
            wsS1[base + (size_t)p * HH] = r1;
            wsS2[base + (size_t)p * HH] = r2;
            wsM[base + (size_t)p * HH]  = rm;
        }
    }
    if (tid < PP) wsS0[(size_t)blk * PP + tid] = s0;
}

// One block per (b,p): reduce partials, build 512-vec, run MLP.
__global__ __launch_bounds__(256) void k2_finish(
    const float* __restrict__ sq,      // [B][P][H]
    const float* __restrict__ W1,      // [4H][HID]
    const float* __restrict__ b1,      // [HID]
    const float* __restrict__ W2,      // [HID][RD]
    const float* __restrict__ b2,      // [RD]
    const float* __restrict__ wsS1, const float* __restrict__ wsS2,
    const float* __restrict__ wsM,  const float* __restrict__ wsS0,
    float* __restrict__ out)           // [B][P][RD]
{
    __shared__ float r[4 * HH];        // residual_input (512)
    __shared__ float part[2 * HID];    // layer-1 k-split partials
    __shared__ float h2[HID];          // hidden activations
    const int blk = blockIdx.x;        // b*PP + p
    const int b = blk >> 4;
    const int p = blk & (PP - 1);
    const int tid = threadIdx.x;

    if (tid < HH) {
        const int h = tid;
        float s1 = 0.f, s2 = 0.f, m = -INFINITY, s0 = 0.f;
        for (int s = 0; s < SS; ++s) {
            size_t idx = ((size_t)(b * SS + s) * PP + p) * HH + h;
            s1 += wsS1[idx];
            s2 += wsS2[idx];
            m = fmaxf(m, wsM[idx]);
            s0 += wsS0[(size_t)(b * SS + s) * PP + p];  // wave-uniform
        }
        float mass = fmaxf(s0, EPSF);
        float pooled = s1 / mass;
        float var = (s2 - 2.f * pooled * s1 + pooled * pooled * s0) / mass;
        float maxf = (m == -INFINITY) ? 0.f : m;
        r[h]          = sq[(size_t)blk * HH + h];
        r[HH + h]     = pooled;
        r[2 * HH + h] = maxf;
        r[3 * HH + h] = var;
    }
    __syncthreads();

    // Layer 1: hdn[j] = relu(b1[j] + sum_k r[k]*W1[k][j]); k split over 2 halves
    {
        const int j = tid & (HID - 1);
        const int half = tid >> 7;
        const int k0 = half * 256;
        float acc = 0.f;
        #pragma unroll 8
        for (int k = 0; k < 256; ++k)
            acc = fmaf(r[k0 + k], W1[(size_t)(k0 + k) * HID + j], acc);
        part[half * HID + j] = acc;
    }
    __syncthreads();
    if (tid < HID)
        h2[tid] = fmaxf(b1[tid] + part[tid] + part[HID + tid], 0.f);
    __syncthreads();

    // Layer 2: out[o] = b2[o] + sum_j h2[j]*W2[j][o]
    if (tid < RD) {
        float acc = b2[tid];
        #pragma unroll 8
        for (int i = 0; i < HID; ++i)
            acc = fmaf(h2[i], W2[(size_t)i * RD + tid], acc);
        out[(size_t)blk * RD + tid] = acc;
    }
}

extern "C" void kernel_launch(void* const* d_in, const int* in_sizes, int n_in,
                              void* d_out, int out_size, void* d_ws, size_t ws_size,
                              hipStream_t stream) {
    const float* sq     = (const float*)d_in[0];
    const float* point  = (const float*)d_in[1];
    const float* assign = (const float*)d_in[2];
    const float* W1     = (const float*)d_in[3];
    const float* b1     = (const float*)d_in[4];
    const float* W2     = (const float*)d_in[5];
    const float* b2     = (const float*)d_in[6];
    float* out = (float*)d_out;

    float* ws = (float*)d_ws;
    const size_t PH = (size_t)BB * SS * PP * HH;  // 524288
    float* wsS1 = ws;
    float* wsS2 = ws + PH;
    float* wsM  = ws + 2 * PH;
    float* wsS0 = ws + 3 * PH;

    k1_partials<<<BB * SS, 256, 0, stream>>>(point, assign, wsS1, wsS2, wsM, wsS0);
    k2_finish<<<BB * PP, 256, 0, stream>>>(sq, W1, b1, W2, b2,
                                           wsS1, wsS2, wsM, wsS0, out);
}

// Round 2
// 109.077 us; speedup vs baseline: 1.1116x; 1.1116x over previous
//
#include <hip/hip_runtime.h>
#include <math.h>

#define BB 8
#define NN 4096
#define PP 16
#define HH 128
#define SS 64          // n-slices
#define NS 64          // n per slice = NN/SS
#define HID 128
#define RD 64
#define EPSF 1e-6f

// Partials per (b, slice): S0[p], S1[p][h], S2[p][h], M[p][h]
__global__ __launch_bounds__(256) void k1_partials(
    const float* __restrict__ point,   // [B][N][H]
    const float* __restrict__ assign,  // [B][N][P]
    float* __restrict__ wsS1, float* __restrict__ wsS2,
    float* __restrict__ wsM,  float* __restrict__ wsS0)
{
    __shared__ float lds_a[NS * PP];        // 4 KB, assign slice
    __shared__ float red[3 * PP * HH];      // 24 KB, cross-sub reduction
    const int blk = blockIdx.x;             // b*SS + s
    const int b = blk >> 6;                 // / SS
    const int s = blk & (SS - 1);
    const int n0 = s * NS;
    const int tid = threadIdx.x;
    const int h = tid & (HH - 1);
    const int sub = tid >> 7;               // 0 or 1

    // stage assign slice: NS*PP = 1024 floats, fully coalesced
    const float* aptr = assign + (size_t)b * NN * PP + (size_t)n0 * PP;
    #pragma unroll
    for (int j = 0; j < (NS * PP) / 256; ++j)
        lds_a[tid + 256 * j] = aptr[tid + 256 * j];
    __syncthreads();

    float s1[PP], s2[PP], m[PP];
    #pragma unroll
    for (int p = 0; p < PP; ++p) { s1[p] = 0.f; s2[p] = 0.f; m[p] = -INFINITY; }

    const float* xptr = point + (size_t)b * NN * HH + (size_t)n0 * HH + h;
    #pragma unroll 4
    for (int nn = sub; nn < NS; nn += 2) {
        float x = xptr[(size_t)nn * HH];
        #pragma unroll
        for (int q = 0; q < 4; ++q) {
            // wave-uniform 16B LDS read -> ds_read_b128 broadcast
            float4 av = *(const float4*)&lds_a[nn * PP + 4 * q];
            float a0 = av.x, a1 = av.y, a2 = av.z, a3 = av.w;
            float t;
            t = a0 * x; s1[4*q+0] += t; s2[4*q+0] = fmaf(t, x, s2[4*q+0]);
            if (a0 > EPSF) m[4*q+0] = fmaxf(m[4*q+0], t);
            t = a1 * x; s1[4*q+1] += t; s2[4*q+1] = fmaf(t, x, s2[4*q+1]);
            if (a1 > EPSF) m[4*q+1] = fmaxf(m[4*q+1], t);
            t = a2 * x; s1[4*q+2] += t; s2[4*q+2] = fmaf(t, x, s2[4*q+2]);
            if (a2 > EPSF) m[4*q+2] = fmaxf(m[4*q+2], t);
            t = a3 * x; s1[4*q+3] += t; s2[4*q+3] = fmaf(t, x, s2[4*q+3]);
            if (a3 > EPSF) m[4*q+3] = fmaxf(m[4*q+3], t);
        }
    }

    // per-p assignment mass over this slice (threads 0..15)
    float s0 = 0.f;
    if (tid < PP) {
        #pragma unroll 8
        for (int nn = 0; nn < NS; ++nn) s0 += lds_a[nn * PP + tid];
    }

    // combine sub=1 into sub=0
    __syncthreads();
    if (sub) {
        #pragma unroll
        for (int p = 0; p < PP; ++p) {
            red[p * HH + h]               = s1[p];
            red[PP * HH + p * HH + h]     = s2[p];
            red[2 * PP * HH + p * HH + h] = m[p];
        }
    }
    __syncthreads();
    if (!sub) {
        size_t base = (size_t)blk * PP * HH + h;
        #pragma unroll
        for (int p = 0; p < PP; ++p) {
            float r1 = s1[p] + red[p * HH + h];
            float r2 = s2[p] + red[PP * HH + p * HH + h];
            float rm = fmaxf(m[p], red[2 * PP * HH + p * HH + h]);
            wsS1[base + (size_t)p * HH] = r1;
            wsS2[base + (size_t)p * HH] = r2;
            wsM[base + (size_t)p * HH]  = rm;
        }
    }
    if (tid < PP) wsS0[(size_t)blk * PP + tid] = s0;
}

// One block per (b,p): reduce partials, build 512-vec, run MLP.
__global__ __launch_bounds__(256) void k2_finish(
    const float* __restrict__ sq,      // [B][P][H]
    const float* __restrict__ W1,      // [4H][HID]
    const float* __restrict__ b1,      // [HID]
    const float* __restrict__ W2,      // [HID][RD]
    const float* __restrict__ b2,      // [RD]
    const float* __restrict__ wsS1, const float* __restrict__ wsS2,
    const float* __restrict__ wsM,  const float* __restrict__ wsS0,
    float* __restrict__ out)           // [B][P][RD]
{
    __shared__ float r[4 * HH];        // residual_input (512)
    __shared__ float red1[HH], red2[HH], redm[HH], red0[1];
    __shared__ float part[2 * HID];    // layer-1 k-split partials
    __shared__ float h2[HID];          // hidden activations
    const int blk = blockIdx.x;        // b*PP + p
    const int b = blk >> 4;
    const int p = blk & (PP - 1);
    const int tid = threadIdx.x;
    const int h = tid & (HH - 1);
    const int sub = tid >> 7;          // which half of the slice range

    float s1 = 0.f, s2 = 0.f, m = -INFINITY, s0 = 0.f;
    const int s_beg = sub * (SS / 2);
    #pragma unroll 4
    for (int si = 0; si < SS / 2; ++si) {
        const int s = s_beg + si;
        size_t idx = ((size_t)(b * SS + s) * PP + p) * HH + h;
        s1 += wsS1[idx];
        s2 += wsS2[idx];
        m = fmaxf(m, wsM[idx]);
        s0 += wsS0[(size_t)(b * SS + s) * PP + p];  // wave-uniform
    }
    if (sub) {
        red1[h] = s1; red2[h] = s2; redm[h] = m;
        if (h == 0) red0[0] = s0;
    }
    __syncthreads();
    if (!sub) {
        s1 += red1[h]; s2 += red2[h]; m = fmaxf(m, redm[h]); s0 += red0[0];
        float mass = fmaxf(s0, EPSF);
        float pooled = s1 / mass;
        float var = (s2 - 2.f * pooled * s1 + pooled * pooled * s0) / mass;
        float maxf = (m == -INFINITY) ? 0.f : m;
        r[h]          = sq[(size_t)blk * HH + h];
        r[HH + h]     = pooled;
        r[2 * HH + h] = maxf;
        r[3 * HH + h] = var;
    }
    __syncthreads();

    // Layer 1: hdn[j] = relu(b1[j] + sum_k r[k]*W1[k][j]); k split over 2 halves
    {
        const int j = tid & (HID - 1);
        const int half = tid >> 7;
        const int k0 = half * 256;
        float acc = 0.f;
        #pragma unroll 8
        for (int k = 0; k < 256; ++k)
            acc = fmaf(r[k0 + k], W1[(size_t)(k0 + k) * HID + j], acc);
        part[half * HID + j] = acc;
    }
    __syncthreads();
    if (tid < HID)
        h2[tid] = fmaxf(b1[tid] + part[tid] + part[HID + tid], 0.f);
    __syncthreads();

    // Layer 2: out[o] = b2[o] + sum_j h2[j]*W2[j][o]
    if (tid < RD) {
        float acc = b2[tid];
        #pragma unroll 8
        for (int i = 0; i < HID; ++i)
            acc = fmaf(h2[i], W2[(size_t)i * RD + tid], acc);
        out[(size_t)blk * RD + tid] = acc;
    }
}

extern "C" void kernel_launch(void* const* d_in, const int* in_sizes, int n_in,
                              void* d_out, int out_size, void* d_ws, size_t ws_size,
                              hipStream_t stream) {
    const float* sq     = (const float*)d_in[0];
    const float* point  = (const float*)d_in[1];
    const float* assign = (const float*)d_in[2];
    const float* W1     = (const float*)d_in[3];
    const float* b1     = (const float*)d_in[4];
    const float* W2     = (const float*)d_in[5];
    const float* b2     = (const float*)d_in[6];
    float* out = (float*)d_out;

    float* ws = (float*)d_ws;
    const size_t PH = (size_t)BB * SS * PP * HH;  // 1048576
    float* wsS1 = ws;
    float* wsS2 = ws + PH;
    float* wsM  = ws + 2 * PH;
    float* wsS0 = ws + 3 * PH;

    k1_partials<<<BB * SS, 256, 0, stream>>>(point, assign, wsS1, wsS2, wsM, wsS0);
    k2_finish<<<BB * PP, 256, 0, stream>>>(sq, W1, b1, W2, b2,
                                           wsS1, wsS2, wsM, wsS0, out);
}